// Round 2
// baseline (805.672 us; speedup 1.0000x reference)
//
#include <hip/hip_runtime.h>
#include <hip/hip_bf16.h>

using v8s = __attribute__((ext_vector_type(8))) short;
using v4f = __attribute__((ext_vector_type(4))) float;

#define DIMC 1792
#define NROW 16384
#define NCEN 4096
#define BIGF 3.0e38f

// direct global->LDS, 16B per lane; LDS dest must be wave-uniform base (+lane*16 implicit)
#define GL2LDS16(g, l) __builtin_amdgcn_global_load_lds(                      \
    (const __attribute__((address_space(1))) void*)(g),                       \
    (__attribute__((address_space(3))) void*)(l), 16, 0, 0)

// ---------- transpose [1792][4096] f32 -> [4096][1792] bf16 (per z) ----------
__global__ void transpose_cvt(const float* __restrict__ in, __hip_bfloat16* __restrict__ out) {
  __shared__ float tile[32][33];
  const int tx = threadIdx.x, ty = threadIdx.y;
  const size_t zoff = (size_t)blockIdx.z * DIMC * NCEN;
  const float* inb = in + zoff;
  __hip_bfloat16* outb = out + zoff;
  const int r0 = blockIdx.y * 32, c0 = blockIdx.x * 32;
#pragma unroll
  for (int j = 0; j < 4; ++j) {
    int rr = ty + j * 8;
    tile[rr][tx] = inb[(size_t)(r0 + rr) * 4096 + c0 + tx];
  }
  __syncthreads();
#pragma unroll
  for (int j = 0; j < 4; ++j) {
    int rr = ty + j * 8;
    outb[(size_t)(c0 + rr) * DIMC + r0 + tx] = __float2bfloat16(tile[tx][rr]);
  }
}

// ---------- W [1792][1794] f32 -> Wb [1792][1792] bf16 ----------
__global__ void w_convert(const float* __restrict__ W, __hip_bfloat16* __restrict__ Wb) {
  int idx = blockIdx.x * 256 + threadIdx.x;
  int o = idx / DIMC, i = idx - o * DIMC;
  Wb[idx] = __float2bfloat16(W[(size_t)o * 1794 + i]);
}

// ---------- dst[row] = sum over 1792 bf16 of v*v ----------
__global__ void rowsq(const __hip_bfloat16* __restrict__ src, float* __restrict__ dst) {
  const int row = blockIdx.x, t = threadIdx.x;
  float s = 0.f;
  if (t < 224) {
    const uint4 v = *(const uint4*)((const unsigned short*)src + (size_t)row * DIMC + t * 8);
    unsigned int u0 = v.x, u1 = v.y, u2 = v.z, u3 = v.w;
    float a, b;
    a = __uint_as_float(u0 << 16); b = __uint_as_float(u0 & 0xFFFF0000u); s += a * a + b * b;
    a = __uint_as_float(u1 << 16); b = __uint_as_float(u1 & 0xFFFF0000u); s += a * a + b * b;
    a = __uint_as_float(u2 << 16); b = __uint_as_float(u2 & 0xFFFF0000u); s += a * a + b * b;
    a = __uint_as_float(u3 << 16); b = __uint_as_float(u3 & 0xFFFF0000u); s += a * a + b * b;
  }
  __shared__ float red[256];
  red[t] = s; __syncthreads();
  for (int off = 128; off > 0; off >>= 1) { if (t < off) red[t] += red[t + off]; __syncthreads(); }
  if (t == 0) dst[row] = red[0];
}

// ---------- GEMM1: phi = Xb * Wb^T + bias + coord terms -> phib bf16 ----------
__global__ __launch_bounds__(256) void gemm_phi(
    const __hip_bfloat16* __restrict__ Xb, const __hip_bfloat16* __restrict__ Wb,
    const float* __restrict__ W, const float* __restrict__ bvec,
    __hip_bfloat16* __restrict__ phib) {
  __shared__ __align__(16) __hip_bfloat16 As[128 * 32];
  __shared__ __align__(16) __hip_bfloat16 Bs[128 * 32];
  const int t = threadIdx.x;
  const int l = t & 63, w = t >> 6, wr = w >> 1, wc = w & 1;
  const int n0 = blockIdx.x * 128, o0 = blockIdx.y * 128;
  // staging: thread t's data lands at LDS byte t*16 (linear dest, rule #21);
  // swizzle applied by pre-permuting the per-lane GLOBAL granule
  const int rowS = t >> 2, gS = (t & 3) ^ ((rowS >> 1) & 3);
  const unsigned short* aP0 = (const unsigned short*)Xb + (size_t)(n0 + rowS) * DIMC + gS * 8;
  const unsigned short* aP1 = aP0 + (size_t)64 * DIMC;
  const unsigned short* bP0 = (const unsigned short*)Wb + (size_t)(o0 + rowS) * DIMC + gS * 8;
  const unsigned short* bP1 = bP0 + (size_t)64 * DIMC;
  // wave-uniform LDS bases (lane*16 added by hardware)
  char* ldsA0 = (char*)As + w * 1024;
  char* ldsA1 = (char*)As + 4096 + w * 1024;
  char* ldsB0 = (char*)Bs + w * 1024;
  char* ldsB1 = (char*)Bs + 4096 + w * 1024;
  // fragment read offsets; physical granule = logical ^ ((row>>1)&3)  (2-way banks)
  const int col = l & 15, g = l >> 4, pr = g ^ ((col >> 1) & 3);
  int offA[4], offB[4];
#pragma unroll
  for (int i = 0; i < 4; ++i) {
    offA[i] = (wr * 64 + i * 16 + col) * 32 + pr * 8;
    offB[i] = (wc * 64 + i * 16 + col) * 32 + pr * 8;
  }
  v4f acc[4][4] = {};
  for (int kt = 0; kt < DIMC; kt += 32) {
    __syncthreads();
    GL2LDS16(aP0 + kt, ldsA0);
    GL2LDS16(aP1 + kt, ldsA1);
    GL2LDS16(bP0 + kt, ldsB0);
    GL2LDS16(bP1 + kt, ldsB1);
    __syncthreads();
    v8s af[4], bf[4];
#pragma unroll
    for (int i = 0; i < 4; ++i) af[i] = *(const v8s*)((const unsigned short*)As + offA[i]);
#pragma unroll
    for (int i = 0; i < 4; ++i) bf[i] = *(const v8s*)((const unsigned short*)Bs + offB[i]);
#pragma unroll
    for (int mi = 0; mi < 4; ++mi)
#pragma unroll
      for (int ni = 0; ni < 4; ++ni)
        acc[mi][ni] = __builtin_amdgcn_mfma_f32_16x16x32_bf16(af[mi], bf[ni], acc[mi][ni], 0, 0, 0);
  }
#pragma unroll
  for (int ni = 0; ni < 4; ++ni) {
    const int o = o0 + wc * 64 + ni * 16 + col;
    const float bo = bvec[o];
    const float wx = W[(size_t)o * 1794 + 1792];
    const float wy = W[(size_t)o * 1794 + 1793];
#pragma unroll
    for (int mi = 0; mi < 4; ++mi) {
#pragma unroll
      for (int j = 0; j < 4; ++j) {
        const int n = n0 + wr * 64 + mi * 16 + g * 4 + j;
        const int wi = n & 63, hi = (n >> 6) & 63;
        const float xxv = -1.f + (2.f / 63.f) * wi;
        const float yyv = -1.f + (2.f / 63.f) * hi;
        float v = acc[mi][ni][j] + bo + wx * xxv + wy * yyv;
        phib[(size_t)n * DIMC + o] = __float2bfloat16(v);
      }
    }
  }
}

// ---------- GEMM2: dist2 = feat2 + cent2 - 2*phi.C ; fused per-wave top-6 ----------
__global__ __launch_bounds__(256) void gemm_dist(
    const __hip_bfloat16* __restrict__ phib, const __hip_bfloat16* __restrict__ Ct,
    const float* __restrict__ feat2, const float* __restrict__ cent2,
    float* __restrict__ cand) {
  __shared__ __align__(16) __hip_bfloat16 As[128 * 32];
  __shared__ __align__(16) __hip_bfloat16 Bs[128 * 32];
  const int t = threadIdx.x;
  const int l = t & 63, w = t >> 6, wr = w >> 1, wc = w & 1;
  const int n0 = blockIdx.x * 128, o0 = blockIdx.y * 128;
  const int rowS = t >> 2, gS = (t & 3) ^ ((rowS >> 1) & 3);
  const unsigned short* aP0 = (const unsigned short*)phib + (size_t)(n0 + rowS) * DIMC + gS * 8;
  const unsigned short* aP1 = aP0 + (size_t)64 * DIMC;
  const unsigned short* bP0 = (const unsigned short*)Ct + (size_t)(o0 + rowS) * DIMC + gS * 8;
  const unsigned short* bP1 = bP0 + (size_t)64 * DIMC;
  char* ldsA0 = (char*)As + w * 1024;
  char* ldsA1 = (char*)As + 4096 + w * 1024;
  char* ldsB0 = (char*)Bs + w * 1024;
  char* ldsB1 = (char*)Bs + 4096 + w * 1024;
  const int col = l & 15, g = l >> 4, pr = g ^ ((col >> 1) & 3);
  int offA[4], offB[4];
#pragma unroll
  for (int i = 0; i < 4; ++i) {
    offA[i] = (wr * 64 + i * 16 + col) * 32 + pr * 8;
    offB[i] = (wc * 64 + i * 16 + col) * 32 + pr * 8;
  }
  v4f acc[4][4] = {};
  for (int kt = 0; kt < DIMC; kt += 32) {
    __syncthreads();
    GL2LDS16(aP0 + kt, ldsA0);
    GL2LDS16(aP1 + kt, ldsA1);
    GL2LDS16(bP0 + kt, ldsB0);
    GL2LDS16(bP1 + kt, ldsB1);
    __syncthreads();
    v8s af[4], bf[4];
#pragma unroll
    for (int i = 0; i < 4; ++i) af[i] = *(const v8s*)((const unsigned short*)As + offA[i]);
#pragma unroll
    for (int i = 0; i < 4; ++i) bf[i] = *(const v8s*)((const unsigned short*)Bs + offB[i]);
#pragma unroll
    for (int mi = 0; mi < 4; ++mi)
#pragma unroll
      for (int ni = 0; ni < 4; ++ni)
        acc[mi][ni] = __builtin_amdgcn_mfma_f32_16x16x32_bf16(af[mi], bf[ni], acc[mi][ni], 0, 0, 0);
  }
  // epilogue: per row (held by one 16-lane group), 64 col values -> 6 smallest
  const unsigned long long gmask = 0xFFFFULL << (g * 16);
  float c2v0 = cent2[o0 + wc * 64 + 0 * 16 + col];
  float c2v1 = cent2[o0 + wc * 64 + 1 * 16 + col];
  float c2v2 = cent2[o0 + wc * 64 + 2 * 16 + col];
  float c2v3 = cent2[o0 + wc * 64 + 3 * 16 + col];
  const int cg = blockIdx.y * 2 + wc;
#pragma unroll
  for (int mi = 0; mi < 4; ++mi) {
#pragma unroll
    for (int j = 0; j < 4; ++j) {
      const int n = n0 + wr * 64 + mi * 16 + g * 4 + j;
      const float f2 = feat2[n];
      float v0 = f2 + c2v0 - 2.f * acc[mi][0][j];
      float v1 = f2 + c2v1 - 2.f * acc[mi][1][j];
      float v2 = f2 + c2v2 - 2.f * acc[mi][2][j];
      float v3 = f2 + c2v3 - 2.f * acc[mi][3][j];
      float mr[6];
#pragma unroll
      for (int r = 0; r < 6; ++r) {
        float m = fminf(fminf(v0, v1), fminf(v2, v3));
        m = fminf(m, __shfl_xor(m, 1));
        m = fminf(m, __shfl_xor(m, 2));
        m = fminf(m, __shfl_xor(m, 4));
        m = fminf(m, __shfl_xor(m, 8));
        bool has = (v0 == m) || (v1 == m) || (v2 == m) || (v3 == m);
        unsigned long long bal = __ballot(has) & gmask;
        int first = (int)(__ffsll(bal) - 1);
        if (l == first) {
          if (v0 == m) v0 = BIGF; else if (v1 == m) v1 = BIGF;
          else if (v2 == m) v2 = BIGF; else v3 = BIGF;
        }
        mr[r] = m;
      }
      if (col == 0) {
        float* cp = cand + ((size_t)n * 64 + cg) * 6;
#pragma unroll
        for (int r = 0; r < 6; ++r) cp[r] = mr[r];
      }
    }
  }
}

// ---------- merge 64 sorted 6-lists per row -> score + rowloss ----------
__global__ void finalize(const float* __restrict__ cand, const float* __restrict__ rvec,
                         float* __restrict__ rowloss, float* __restrict__ score) {
  const int n = blockIdx.x, l = threadIdx.x;
  const float* cp = cand + ((size_t)n * 64 + l) * 6;
  float c0 = cp[0], c1 = cp[1], c2 = cp[2], c3 = cp[3], c4 = cp[4], c5 = cp[5];
  int ptr = 0;
  float d6[6];
#pragma unroll
  for (int r = 0; r < 6; ++r) {
    float v = (ptr == 0) ? c0 : (ptr == 1) ? c1 : (ptr == 2) ? c2
            : (ptr == 3) ? c3 : (ptr == 4) ? c4 : (ptr == 5) ? c5 : BIGF;
    float m = v;
    m = fminf(m, __shfl_xor(m, 1));
    m = fminf(m, __shfl_xor(m, 2));
    m = fminf(m, __shfl_xor(m, 4));
    m = fminf(m, __shfl_xor(m, 8));
    m = fminf(m, __shfl_xor(m, 16));
    m = fminf(m, __shfl_xor(m, 32));
    unsigned long long bal = __ballot(v == m);
    if (l == (int)(__ffsll(bal) - 1)) ptr++;
    d6[r] = m;
  }
  if (l == 0) {
    const float r2 = rvec[0] * rvec[0];
    float att = 0.f, rep = 0.f;
#pragma unroll
    for (int i = 0; i < 3; ++i) att += fmaxf(d6[i] - r2, 0.f);
#pragma unroll
    for (int i = 3; i < 6; ++i) rep += fmaxf(r2 - d6[i] - 0.1f, 0.f);
    rowloss[n] = att + rep;
    float dk0 = sqrtf(fmaxf(d6[0], 0.f));
    float dk1 = sqrtf(fmaxf(d6[1], 0.f));
    float dk2 = sqrtf(fmaxf(d6[2], 0.f));
    float e1 = expf(dk0 - dk1), e2 = expf(dk0 - dk2);
    score[n] = dk0 / (1.f + e1 + e2);
  }
}

__global__ void reduce_loss(const float* __restrict__ rowloss, float* __restrict__ out) {
  const int t = threadIdx.x;
  float s = 0.f;
  for (int i = t; i < NROW; i += 256) s += rowloss[i];
  __shared__ float red[256];
  red[t] = s; __syncthreads();
  for (int off = 128; off > 0; off >>= 1) { if (t < off) red[t] += red[t + off]; __syncthreads(); }
  if (t == 0) out[0] = red[0] / (0.001f * 49152.f);  // (1/NU)/(B*HW*K)
}

extern "C" void kernel_launch(void* const* d_in, const int* in_sizes, int n_in,
                              void* d_out, int out_size, void* d_ws, size_t ws_size,
                              hipStream_t stream) {
  const float* sample = (const float*)d_in[0];
  const float* W      = (const float*)d_in[1];
  const float* bvec   = (const float*)d_in[2];
  const float* C      = (const float*)d_in[3];
  const float* rv     = (const float*)d_in[4];
  float* out = (float*)d_out;

  char* p = (char*)d_ws;
  auto take = [&](size_t bytes) { char* q = p; p += (bytes + 255) & ~(size_t)255; return q; };
  __hip_bfloat16* Xb   = (__hip_bfloat16*)take((size_t)NROW * DIMC * 2);
  __hip_bfloat16* Wb   = (__hip_bfloat16*)take((size_t)DIMC * DIMC * 2);
  __hip_bfloat16* Ct   = (__hip_bfloat16*)take((size_t)NCEN * DIMC * 2);
  __hip_bfloat16* phib = (__hip_bfloat16*)take((size_t)NROW * DIMC * 2);
  float* feat2   = (float*)take((size_t)NROW * 4);
  float* cent2   = (float*)take((size_t)NCEN * 4);
  float* cand    = (float*)take((size_t)NROW * 64 * 6 * 4);
  float* rowloss = (float*)take((size_t)NROW * 4);

  transpose_cvt<<<dim3(128, 56, 4), dim3(32, 8), 0, stream>>>(sample, Xb);
  transpose_cvt<<<dim3(128, 56, 1), dim3(32, 8), 0, stream>>>(C, Ct);
  w_convert<<<dim3(12544), dim3(256), 0, stream>>>(W, Wb);
  rowsq<<<dim3(NCEN), dim3(256), 0, stream>>>(Ct, cent2);
  gemm_phi<<<dim3(128, 14), dim3(256), 0, stream>>>(Xb, Wb, W, bvec, phib);
  rowsq<<<dim3(NROW), dim3(256), 0, stream>>>(phib, feat2);
  gemm_dist<<<dim3(128, 32), dim3(256), 0, stream>>>(phib, Ct, feat2, cent2, cand);
  finalize<<<dim3(NROW), dim3(64), 0, stream>>>(cand, rv, rowloss, out + 1);
  reduce_loss<<<dim3(1), dim3(256), 0, stream>>>(rowloss, out);
}

// Round 6
// 728.407 us; speedup vs baseline: 1.1061x; 1.1061x over previous
//
#include <hip/hip_runtime.h>
#include <hip/hip_bf16.h>

using v8s = __attribute__((ext_vector_type(8))) short;
using v4f = __attribute__((ext_vector_type(4))) float;

#define DIMC 1792
#define NROW 16384
#define NCEN 4096
#define BIGF 3.0e38f

// direct global->LDS, 16B per lane; LDS dest must be wave-uniform base (+lane*16 implicit)
#define GL2LDS16(g, l) __builtin_amdgcn_global_load_lds(                      \
    (const __attribute__((address_space(1))) void*)(g),                       \
    (__attribute__((address_space(3))) void*)(l), 16, 0, 0)

__device__ __forceinline__ void ce(float& a, float& b) {
  float lo = fminf(a, b), hi = fmaxf(a, b); a = lo; b = hi;
}

// merge this lane's sorted-ascending 6-list with partner lane's (xor MASK);
// result: sorted-ascending 6 smallest of the 12 (identical on both lanes).
template<int MASK>
__device__ __forceinline__ void merge6(float s[6]) {
  float p[6];
#pragma unroll
  for (int i = 0; i < 6; ++i) p[i] = __shfl_xor(s[i], MASK);
  float t[6];
#pragma unroll
  for (int i = 0; i < 6; ++i) t[i] = fminf(s[i], p[5 - i]);
  // t is bitonic; half-clean + two 3-sorters -> sorted
  ce(t[0], t[3]); ce(t[1], t[4]); ce(t[2], t[5]);
  ce(t[0], t[2]); ce(t[0], t[1]); ce(t[1], t[2]);
  ce(t[3], t[5]); ce(t[3], t[4]); ce(t[4], t[5]);
#pragma unroll
  for (int i = 0; i < 6; ++i) s[i] = t[i];
}

// ---------- transpose [1792][4096] f32 -> [4096][1792] bf16 (per z) ----------
__global__ void transpose_cvt(const float* __restrict__ in, __hip_bfloat16* __restrict__ out) {
  __shared__ float tile[32][33];
  const int tx = threadIdx.x, ty = threadIdx.y;
  const size_t zoff = (size_t)blockIdx.z * DIMC * NCEN;
  const float* inb = in + zoff;
  __hip_bfloat16* outb = out + zoff;
  const int r0 = blockIdx.y * 32, c0 = blockIdx.x * 32;
#pragma unroll
  for (int j = 0; j < 4; ++j) {
    int rr = ty + j * 8;
    tile[rr][tx] = inb[(size_t)(r0 + rr) * 4096 + c0 + tx];
  }
  __syncthreads();
#pragma unroll
  for (int j = 0; j < 4; ++j) {
    int rr = ty + j * 8;
    outb[(size_t)(c0 + rr) * DIMC + r0 + tx] = __float2bfloat16(tile[tx][rr]);
  }
}

// ---------- W [1792][1794] f32 -> Wb [1792][1792] bf16 ----------
__global__ void w_convert(const float* __restrict__ W, __hip_bfloat16* __restrict__ Wb) {
  int idx = blockIdx.x * 256 + threadIdx.x;
  int o = idx / DIMC, i = idx - o * DIMC;
  Wb[idx] = __float2bfloat16(W[(size_t)o * 1794 + i]);
}

// ---------- dst[row] = sum over 1792 bf16 of v*v ----------
__global__ void rowsq(const __hip_bfloat16* __restrict__ src, float* __restrict__ dst) {
  const int row = blockIdx.x, t = threadIdx.x;
  float s = 0.f;
  if (t < 224) {
    const uint4 v = *(const uint4*)((const unsigned short*)src + (size_t)row * DIMC + t * 8);
    unsigned int u0 = v.x, u1 = v.y, u2 = v.z, u3 = v.w;
    float a, b;
    a = __uint_as_float(u0 << 16); b = __uint_as_float(u0 & 0xFFFF0000u); s += a * a + b * b;
    a = __uint_as_float(u1 << 16); b = __uint_as_float(u1 & 0xFFFF0000u); s += a * a + b * b;
    a = __uint_as_float(u2 << 16); b = __uint_as_float(u2 & 0xFFFF0000u); s += a * a + b * b;
    a = __uint_as_float(u3 << 16); b = __uint_as_float(u3 & 0xFFFF0000u); s += a * a + b * b;
  }
  __shared__ float red[256];
  red[t] = s; __syncthreads();
  for (int off = 128; off > 0; off >>= 1) { if (t < off) red[t] += red[t + off]; __syncthreads(); }
  if (t == 0) dst[row] = red[0];
}

// ---------- GEMM1: phi = Xb * Wb^T + bias + coord terms -> phib bf16 ----------
__global__ __launch_bounds__(256) void gemm_phi(
    const __hip_bfloat16* __restrict__ Xb, const __hip_bfloat16* __restrict__ Wb,
    const float* __restrict__ W, const float* __restrict__ bvec,
    __hip_bfloat16* __restrict__ phib) {
  __shared__ __align__(16) __hip_bfloat16 As[128 * 32];
  __shared__ __align__(16) __hip_bfloat16 Bs[128 * 32];
  const int t = threadIdx.x;
  const int l = t & 63, w = t >> 6, wr = w >> 1, wc = w & 1;
  const int n0 = blockIdx.x * 128, o0 = blockIdx.y * 128;
  const int rowS = t >> 2, gS = (t & 3) ^ ((rowS >> 1) & 3);
  const unsigned short* aP0 = (const unsigned short*)Xb + (size_t)(n0 + rowS) * DIMC + gS * 8;
  const unsigned short* aP1 = aP0 + (size_t)64 * DIMC;
  const unsigned short* bP0 = (const unsigned short*)Wb + (size_t)(o0 + rowS) * DIMC + gS * 8;
  const unsigned short* bP1 = bP0 + (size_t)64 * DIMC;
  char* ldsA0 = (char*)As + w * 1024;
  char* ldsA1 = (char*)As + 4096 + w * 1024;
  char* ldsB0 = (char*)Bs + w * 1024;
  char* ldsB1 = (char*)Bs + 4096 + w * 1024;
  const int col = l & 15, g = l >> 4, pr = g ^ ((col >> 1) & 3);
  int offA[4], offB[4];
#pragma unroll
  for (int i = 0; i < 4; ++i) {
    offA[i] = (wr * 64 + i * 16 + col) * 32 + pr * 8;
    offB[i] = (wc * 64 + i * 16 + col) * 32 + pr * 8;
  }
  v4f acc[4][4] = {};
  for (int kt = 0; kt < DIMC; kt += 32) {
    __syncthreads();
    GL2LDS16(aP0 + kt, ldsA0);
    GL2LDS16(aP1 + kt, ldsA1);
    GL2LDS16(bP0 + kt, ldsB0);
    GL2LDS16(bP1 + kt, ldsB1);
    __syncthreads();
    v8s af[4], bf[4];
#pragma unroll
    for (int i = 0; i < 4; ++i) af[i] = *(const v8s*)((const unsigned short*)As + offA[i]);
#pragma unroll
    for (int i = 0; i < 4; ++i) bf[i] = *(const v8s*)((const unsigned short*)Bs + offB[i]);
#pragma unroll
    for (int mi = 0; mi < 4; ++mi)
#pragma unroll
      for (int ni = 0; ni < 4; ++ni)
        acc[mi][ni] = __builtin_amdgcn_mfma_f32_16x16x32_bf16(af[mi], bf[ni], acc[mi][ni], 0, 0, 0);
  }
#pragma unroll
  for (int ni = 0; ni < 4; ++ni) {
    const int o = o0 + wc * 64 + ni * 16 + col;
    const float bo = bvec[o];
    const float wx = W[(size_t)o * 1794 + 1792];
    const float wy = W[(size_t)o * 1794 + 1793];
#pragma unroll
    for (int mi = 0; mi < 4; ++mi) {
#pragma unroll
      for (int j = 0; j < 4; ++j) {
        const int n = n0 + wr * 64 + mi * 16 + g * 4 + j;
        const int wi = n & 63, hi = (n >> 6) & 63;
        const float xxv = -1.f + (2.f / 63.f) * wi;
        const float yyv = -1.f + (2.f / 63.f) * hi;
        float v = acc[mi][ni][j] + bo + wx * xxv + wy * yyv;
        phib[(size_t)n * DIMC + o] = __float2bfloat16(v);
      }
    }
  }
}

// ---------- GEMM2: dist2 = feat2 + cent2 - 2*phi.C ; fused bitonic top-6 ----------
__global__ __launch_bounds__(256) void gemm_dist(
    const __hip_bfloat16* __restrict__ phib, const __hip_bfloat16* __restrict__ Ct,
    const float* __restrict__ feat2, const float* __restrict__ cent2,
    float* __restrict__ cand) {
  __shared__ __align__(16) __hip_bfloat16 As[128 * 32];
  __shared__ __align__(16) __hip_bfloat16 Bs[128 * 32];
  const int t = threadIdx.x;
  const int l = t & 63, w = t >> 6, wr = w >> 1, wc = w & 1;
  const int n0 = blockIdx.x * 128, o0 = blockIdx.y * 128;
  const int rowS = t >> 2, gS = (t & 3) ^ ((rowS >> 1) & 3);
  const unsigned short* aP0 = (const unsigned short*)phib + (size_t)(n0 + rowS) * DIMC + gS * 8;
  const unsigned short* aP1 = aP0 + (size_t)64 * DIMC;
  const unsigned short* bP0 = (const unsigned short*)Ct + (size_t)(o0 + rowS) * DIMC + gS * 8;
  const unsigned short* bP1 = bP0 + (size_t)64 * DIMC;
  char* ldsA0 = (char*)As + w * 1024;
  char* ldsA1 = (char*)As + 4096 + w * 1024;
  char* ldsB0 = (char*)Bs + w * 1024;
  char* ldsB1 = (char*)Bs + 4096 + w * 1024;
  const int col = l & 15, g = l >> 4, pr = g ^ ((col >> 1) & 3);
  int offA[4], offB[4];
#pragma unroll
  for (int i = 0; i < 4; ++i) {
    offA[i] = (wr * 64 + i * 16 + col) * 32 + pr * 8;
    offB[i] = (wc * 64 + i * 16 + col) * 32 + pr * 8;
  }
  v4f acc[4][4] = {};
  for (int kt = 0; kt < DIMC; kt += 32) {
    __syncthreads();
    GL2LDS16(aP0 + kt, ldsA0);
    GL2LDS16(aP1 + kt, ldsA1);
    GL2LDS16(bP0 + kt, ldsB0);
    GL2LDS16(bP1 + kt, ldsB1);
    __syncthreads();
    v8s af[4], bf[4];
#pragma unroll
    for (int i = 0; i < 4; ++i) af[i] = *(const v8s*)((const unsigned short*)As + offA[i]);
#pragma unroll
    for (int i = 0; i < 4; ++i) bf[i] = *(const v8s*)((const unsigned short*)Bs + offB[i]);
#pragma unroll
    for (int mi = 0; mi < 4; ++mi)
#pragma unroll
      for (int ni = 0; ni < 4; ++ni)
        acc[mi][ni] = __builtin_amdgcn_mfma_f32_16x16x32_bf16(af[mi], bf[ni], acc[mi][ni], 0, 0, 0);
  }
  // epilogue: per row (16-lane group g), 64 col values -> sorted 6 smallest
  float c2v0 = cent2[o0 + wc * 64 + 0 * 16 + col];
  float c2v1 = cent2[o0 + wc * 64 + 1 * 16 + col];
  float c2v2 = cent2[o0 + wc * 64 + 2 * 16 + col];
  float c2v3 = cent2[o0 + wc * 64 + 3 * 16 + col];
  const int cg = blockIdx.y * 2 + wc;
#pragma unroll
  for (int mi = 0; mi < 4; ++mi) {
#pragma unroll
    for (int j = 0; j < 4; ++j) {
      const int n = n0 + wr * 64 + mi * 16 + g * 4 + j;
      const float f2 = feat2[n];
      float s[6];
      s[0] = f2 + c2v0 - 2.f * acc[mi][0][j];
      s[1] = f2 + c2v1 - 2.f * acc[mi][1][j];
      s[2] = f2 + c2v2 - 2.f * acc[mi][2][j];
      s[3] = f2 + c2v3 - 2.f * acc[mi][3][j];
      // sort 4 ascending (5-CE network), pad to 6
      ce(s[0], s[1]); ce(s[2], s[3]); ce(s[0], s[2]); ce(s[1], s[3]); ce(s[1], s[2]);
      s[4] = BIGF; s[5] = BIGF;
      merge6<1>(s); merge6<2>(s); merge6<4>(s); merge6<8>(s);
      if (col == 0) {
        float* cp = cand + ((size_t)n * 64 + cg) * 6;
#pragma unroll
        for (int r = 0; r < 6; ++r) cp[r] = s[r];
      }
    }
  }
}

// ---------- merge 64 sorted 6-lists per row -> score + rowloss ----------
__global__ void finalize(const float* __restrict__ cand, const float* __restrict__ rvec,
                         float* __restrict__ rowloss, float* __restrict__ score) {
  const int n = blockIdx.x, l = threadIdx.x;
  const float* cp = cand + ((size_t)n * 64 + l) * 6;
  float s[6];
#pragma unroll
  for (int i = 0; i < 6; ++i) s[i] = cp[i];
  merge6<1>(s); merge6<2>(s); merge6<4>(s); merge6<8>(s); merge6<16>(s); merge6<32>(s);
  if (l == 0) {
    const float r2 = rvec[0] * rvec[0];
    float att = 0.f, rep = 0.f;
#pragma unroll
    for (int i = 0; i < 3; ++i) att += fmaxf(s[i] - r2, 0.f);
#pragma unroll
    for (int i = 3; i < 6; ++i) rep += fmaxf(r2 - s[i] - 0.1f, 0.f);
    rowloss[n] = att + rep;
    float dk0 = sqrtf(fmaxf(s[0], 0.f));
    float dk1 = sqrtf(fmaxf(s[1], 0.f));
    float dk2 = sqrtf(fmaxf(s[2], 0.f));
    float e1 = expf(dk0 - dk1), e2 = expf(dk0 - dk2);
    score[n] = dk0 / (1.f + e1 + e2);
  }
}

__global__ void reduce_loss(const float* __restrict__ rowloss, float* __restrict__ out) {
  const int t = threadIdx.x;
  float s = 0.f;
  for (int i = t; i < NROW; i += 256) s += rowloss[i];
  __shared__ float red[256];
  red[t] = s; __syncthreads();
  for (int off = 128; off > 0; off >>= 1) { if (t < off) red[t] += red[t + off]; __syncthreads(); }
  if (t == 0) out[0] = red[0] / (0.001f * 49152.f);  // (1/NU)/(B*HW*K)
}

extern "C" void kernel_launch(void* const* d_in, const int* in_sizes, int n_in,
                              void* d_out, int out_size, void* d_ws, size_t ws_size,
                              hipStream_t stream) {
  const float* sample = (const float*)d_in[0];
  const float* W      = (const float*)d_in[1];
  const float* bvec   = (const float*)d_in[2];
  const float* C      = (const float*)d_in[3];
  const float* rv     = (const float*)d_in[4];
  float* out = (float*)d_out;

  char* p = (char*)d_ws;
  auto take = [&](size_t bytes) { char* q = p; p += (bytes + 255) & ~(size_t)255; return q; };
  __hip_bfloat16* Xb   = (__hip_bfloat16*)take((size_t)NROW * DIMC * 2);
  __hip_bfloat16* Wb   = (__hip_bfloat16*)take((size_t)DIMC * DIMC * 2);
  __hip_bfloat16* Ct   = (__hip_bfloat16*)take((size_t)NCEN * DIMC * 2);
  __hip_bfloat16* phib = (__hip_bfloat16*)take((size_t)NROW * DIMC * 2);
  float* feat2   = (float*)take((size_t)NROW * 4);
  float* cent2   = (float*)take((size_t)NCEN * 4);
  float* cand    = (float*)take((size_t)NROW * 64 * 6 * 4);
  float* rowloss = (float*)take((size_t)NROW * 4);

  transpose_cvt<<<dim3(128, 56, 4), dim3(32, 8), 0, stream>>>(sample, Xb);
  transpose_cvt<<<dim3(128, 56, 1), dim3(32, 8), 0, stream>>>(C, Ct);
  w_convert<<<dim3(12544), dim3(256), 0, stream>>>(W, Wb);
  rowsq<<<dim3(NCEN), dim3(256), 0, stream>>>(Ct, cent2);
  gemm_phi<<<dim3(128, 14), dim3(256), 0, stream>>>(Xb, Wb, W, bvec, phib);
  rowsq<<<dim3(NROW), dim3(256), 0, stream>>>(phib, feat2);
  gemm_dist<<<dim3(128, 32), dim3(256), 0, stream>>>(phib, Ct, feat2, cent2, cand);
  finalize<<<dim3(NROW), dim3(64), 0, stream>>>(cand, rv, rowloss, out + 1);
  reduce_loss<<<dim3(1), dim3(256), 0, stream>>>(rowloss, out);
}

// Round 7
// 714.789 us; speedup vs baseline: 1.1271x; 1.0191x over previous
//
#include <hip/hip_runtime.h>
#include <hip/hip_bf16.h>

using v8s = __attribute__((ext_vector_type(8))) short;
using v4f = __attribute__((ext_vector_type(4))) float;

#define DIMC 1792
#define NROW 16384
#define NCEN 4096
#define BIGF 3.0e38f

// direct global->LDS, 16B per lane; LDS dest must be wave-uniform base (+lane*16 implicit)
#define GL2LDS16(g, l) __builtin_amdgcn_global_load_lds(                      \
    (const __attribute__((address_space(1))) void*)(g),                       \
    (__attribute__((address_space(3))) void*)(l), 16, 0, 0)

// counted-vmcnt fence + raw barrier (NO __syncthreads: compiler would drain vmcnt(0))
#define FENCE_BAR(N) do {                                                     \
    asm volatile("s_waitcnt vmcnt(" #N ")" ::: "memory");                     \
    __builtin_amdgcn_sched_barrier(0);                                        \
    __builtin_amdgcn_s_barrier();                                             \
    __builtin_amdgcn_sched_barrier(0);                                        \
  } while (0)

__device__ __forceinline__ void ce(float& a, float& b) {
  float lo = fminf(a, b), hi = fmaxf(a, b); a = lo; b = hi;
}

// merge this lane's sorted-ascending 6-list with partner lane's (xor MASK);
// result: sorted-ascending 6 smallest of the 12 (identical on both lanes).
template<int MASK>
__device__ __forceinline__ void merge6(float s[6]) {
  float p[6];
#pragma unroll
  for (int i = 0; i < 6; ++i) p[i] = __shfl_xor(s[i], MASK);
  float t[6];
#pragma unroll
  for (int i = 0; i < 6; ++i) t[i] = fminf(s[i], p[5 - i]);
  ce(t[0], t[3]); ce(t[1], t[4]); ce(t[2], t[5]);
  ce(t[0], t[2]); ce(t[0], t[1]); ce(t[1], t[2]);
  ce(t[3], t[5]); ce(t[3], t[4]); ce(t[4], t[5]);
#pragma unroll
  for (int i = 0; i < 6; ++i) s[i] = t[i];
}

// ---------- transpose [1792][4096] f32 -> [4096][1792] bf16 (per z) ----------
__global__ void transpose_cvt(const float* __restrict__ in, __hip_bfloat16* __restrict__ out) {
  __shared__ float tile[32][33];
  const int tx = threadIdx.x, ty = threadIdx.y;
  const size_t zoff = (size_t)blockIdx.z * DIMC * NCEN;
  const float* inb = in + zoff;
  __hip_bfloat16* outb = out + zoff;
  const int r0 = blockIdx.y * 32, c0 = blockIdx.x * 32;
#pragma unroll
  for (int j = 0; j < 4; ++j) {
    int rr = ty + j * 8;
    tile[rr][tx] = inb[(size_t)(r0 + rr) * 4096 + c0 + tx];
  }
  __syncthreads();
#pragma unroll
  for (int j = 0; j < 4; ++j) {
    int rr = ty + j * 8;
    outb[(size_t)(c0 + rr) * DIMC + r0 + tx] = __float2bfloat16(tile[tx][rr]);
  }
}

// ---------- W [1792][1794] f32 -> Wb [1792][1792] bf16 ----------
__global__ void w_convert(const float* __restrict__ W, __hip_bfloat16* __restrict__ Wb) {
  int idx = blockIdx.x * 256 + threadIdx.x;
  int o = idx / DIMC, i = idx - o * DIMC;
  Wb[idx] = __float2bfloat16(W[(size_t)o * 1794 + i]);
}

// ---------- dst[row] = sum over 1792 bf16 of v*v ----------
__global__ void rowsq(const __hip_bfloat16* __restrict__ src, float* __restrict__ dst) {
  const int row = blockIdx.x, t = threadIdx.x;
  float s = 0.f;
  if (t < 224) {
    const uint4 v = *(const uint4*)((const unsigned short*)src + (size_t)row * DIMC + t * 8);
    unsigned int u0 = v.x, u1 = v.y, u2 = v.z, u3 = v.w;
    float a, b;
    a = __uint_as_float(u0 << 16); b = __uint_as_float(u0 & 0xFFFF0000u); s += a * a + b * b;
    a = __uint_as_float(u1 << 16); b = __uint_as_float(u1 & 0xFFFF0000u); s += a * a + b * b;
    a = __uint_as_float(u2 << 16); b = __uint_as_float(u2 & 0xFFFF0000u); s += a * a + b * b;
    a = __uint_as_float(u3 << 16); b = __uint_as_float(u3 & 0xFFFF0000u); s += a * a + b * b;
  }
  __shared__ float red[256];
  red[t] = s; __syncthreads();
  for (int off = 128; off > 0; off >>= 1) { if (t < off) red[t] += red[t + off]; __syncthreads(); }
  if (t == 0) dst[row] = red[0];
}

// ---------- GEMM1: phi = Xb * Wb^T + bias + coord terms -> phib bf16 ----------
// triple-buffered K-loop, counted vmcnt, 1 raw barrier per K-step
__global__ __launch_bounds__(256) void gemm_phi(
    const __hip_bfloat16* __restrict__ Xb, const __hip_bfloat16* __restrict__ Wb,
    const float* __restrict__ W, const float* __restrict__ bvec,
    __hip_bfloat16* __restrict__ phib) {
  __shared__ __align__(16) char L[49152];
  const int t = threadIdx.x;
  const int l = t & 63, w = t >> 6, wr = w >> 1, wc = w & 1;
  const int n0 = blockIdx.x * 128, o0 = blockIdx.y * 128;
  const int rowS = t >> 2, gS = (t & 3) ^ ((rowS >> 1) & 3);
  const unsigned short* aP0 = (const unsigned short*)Xb + (size_t)(n0 + rowS) * DIMC + gS * 8;
  const unsigned short* aP1 = aP0 + (size_t)64 * DIMC;
  const unsigned short* bP0 = (const unsigned short*)Wb + (size_t)(o0 + rowS) * DIMC + gS * 8;
  const unsigned short* bP1 = bP0 + (size_t)64 * DIMC;
  char* A0 = L;         char* A1 = L + 8192;  char* A2 = L + 16384;
  char* B0 = L + 24576; char* B1 = L + 32768; char* B2 = L + 40960;
  const int woff = w * 1024;
  const int col = l & 15, g = l >> 4, pr = g ^ ((col >> 1) & 3);
  int offA[4], offB[4];  // byte offsets within a buffer
#pragma unroll
  for (int i = 0; i < 4; ++i) {
    offA[i] = ((wr * 64 + i * 16 + col) * 32 + pr * 8) * 2;
    offB[i] = ((wc * 64 + i * 16 + col) * 32 + pr * 8) * 2;
  }
  v4f acc[4][4] = {};
  auto stage = [&](int ke, char* sA, char* sB) {
    GL2LDS16(aP0 + ke, sA + woff);
    GL2LDS16(aP1 + ke, sA + 4096 + woff);
    GL2LDS16(bP0 + ke, sB + woff);
    GL2LDS16(bP1 + ke, sB + 4096 + woff);
  };
  auto compute = [&](const char* rA, const char* rB) {
    v8s af[4], bf[4];
#pragma unroll
    for (int i = 0; i < 4; ++i) af[i] = *(const v8s*)(rA + offA[i]);
#pragma unroll
    for (int i = 0; i < 4; ++i) bf[i] = *(const v8s*)(rB + offB[i]);
#pragma unroll
    for (int mi = 0; mi < 4; ++mi)
#pragma unroll
      for (int ni = 0; ni < 4; ++ni)
        acc[mi][ni] = __builtin_amdgcn_mfma_f32_16x16x32_bf16(af[mi], bf[ni], acc[mi][ni], 0, 0, 0);
  };
  stage(0, A0, B0);
  stage(32, A1, B1);
  FENCE_BAR(4);
  for (int k3 = 0; k3 < 54; k3 += 3) {  // DIMC/32 = 56 tiles; 0..53 here, 54/55 in tail
    stage((k3 + 2) * 32, A2, B2); compute(A0, B0); FENCE_BAR(4);
    stage((k3 + 3) * 32, A0, B0); compute(A1, B1); FENCE_BAR(4);
    stage((k3 + 4) * 32, A1, B1); compute(A2, B2); FENCE_BAR(4);
  }
  compute(A0, B0);  // tile 54
  FENCE_BAR(0);     // force tile 55 landed
  compute(A1, B1);  // tile 55
#pragma unroll
  for (int ni = 0; ni < 4; ++ni) {
    const int o = o0 + wc * 64 + ni * 16 + col;
    const float bo = bvec[o];
    const float wx = W[(size_t)o * 1794 + 1792];
    const float wy = W[(size_t)o * 1794 + 1793];
#pragma unroll
    for (int mi = 0; mi < 4; ++mi) {
#pragma unroll
      for (int j = 0; j < 4; ++j) {
        const int n = n0 + wr * 64 + mi * 16 + g * 4 + j;
        const int wi = n & 63, hi = (n >> 6) & 63;
        const float xxv = -1.f + (2.f / 63.f) * wi;
        const float yyv = -1.f + (2.f / 63.f) * hi;
        float v = acc[mi][ni][j] + bo + wx * xxv + wy * yyv;
        phib[(size_t)n * DIMC + o] = __float2bfloat16(v);
      }
    }
  }
}

// ---------- GEMM2: dist2 = feat2 + cent2 - 2*phi.C ; fused bitonic top-6 ----------
__global__ __launch_bounds__(256) void gemm_dist(
    const __hip_bfloat16* __restrict__ phib, const __hip_bfloat16* __restrict__ Ct,
    const float* __restrict__ feat2, const float* __restrict__ cent2,
    float* __restrict__ cand) {
  __shared__ __align__(16) char L[49152];
  const int t = threadIdx.x;
  const int l = t & 63, w = t >> 6, wr = w >> 1, wc = w & 1;
  const int n0 = blockIdx.x * 128, o0 = blockIdx.y * 128;
  const int rowS = t >> 2, gS = (t & 3) ^ ((rowS >> 1) & 3);
  const unsigned short* aP0 = (const unsigned short*)phib + (size_t)(n0 + rowS) * DIMC + gS * 8;
  const unsigned short* aP1 = aP0 + (size_t)64 * DIMC;
  const unsigned short* bP0 = (const unsigned short*)Ct + (size_t)(o0 + rowS) * DIMC + gS * 8;
  const unsigned short* bP1 = bP0 + (size_t)64 * DIMC;
  char* A0 = L;         char* A1 = L + 8192;  char* A2 = L + 16384;
  char* B0 = L + 24576; char* B1 = L + 32768; char* B2 = L + 40960;
  const int woff = w * 1024;
  const int col = l & 15, g = l >> 4, pr = g ^ ((col >> 1) & 3);
  int offA[4], offB[4];
#pragma unroll
  for (int i = 0; i < 4; ++i) {
    offA[i] = ((wr * 64 + i * 16 + col) * 32 + pr * 8) * 2;
    offB[i] = ((wc * 64 + i * 16 + col) * 32 + pr * 8) * 2;
  }
  v4f acc[4][4] = {};
  auto stage = [&](int ke, char* sA, char* sB) {
    GL2LDS16(aP0 + ke, sA + woff);
    GL2LDS16(aP1 + ke, sA + 4096 + woff);
    GL2LDS16(bP0 + ke, sB + woff);
    GL2LDS16(bP1 + ke, sB + 4096 + woff);
  };
  auto compute = [&](const char* rA, const char* rB) {
    v8s af[4], bf[4];
#pragma unroll
    for (int i = 0; i < 4; ++i) af[i] = *(const v8s*)(rA + offA[i]);
#pragma unroll
    for (int i = 0; i < 4; ++i) bf[i] = *(const v8s*)(rB + offB[i]);
#pragma unroll
    for (int mi = 0; mi < 4; ++mi)
#pragma unroll
      for (int ni = 0; ni < 4; ++ni)
        acc[mi][ni] = __builtin_amdgcn_mfma_f32_16x16x32_bf16(af[mi], bf[ni], acc[mi][ni], 0, 0, 0);
  };
  stage(0, A0, B0);
  stage(32, A1, B1);
  FENCE_BAR(4);
  for (int k3 = 0; k3 < 54; k3 += 3) {
    stage((k3 + 2) * 32, A2, B2); compute(A0, B0); FENCE_BAR(4);
    stage((k3 + 3) * 32, A0, B0); compute(A1, B1); FENCE_BAR(4);
    stage((k3 + 4) * 32, A1, B1); compute(A2, B2); FENCE_BAR(4);
  }
  compute(A0, B0);
  FENCE_BAR(0);
  compute(A1, B1);
  // epilogue: per row (16-lane group g), 64 col values -> sorted 6 smallest
  float c2v0 = cent2[o0 + wc * 64 + 0 * 16 + col];
  float c2v1 = cent2[o0 + wc * 64 + 1 * 16 + col];
  float c2v2 = cent2[o0 + wc * 64 + 2 * 16 + col];
  float c2v3 = cent2[o0 + wc * 64 + 3 * 16 + col];
  const int cg = blockIdx.y * 2 + wc;
#pragma unroll
  for (int mi = 0; mi < 4; ++mi) {
#pragma unroll
    for (int j = 0; j < 4; ++j) {
      const int n = n0 + wr * 64 + mi * 16 + g * 4 + j;
      const float f2 = feat2[n];
      float s[6];
      s[0] = f2 + c2v0 - 2.f * acc[mi][0][j];
      s[1] = f2 + c2v1 - 2.f * acc[mi][1][j];
      s[2] = f2 + c2v2 - 2.f * acc[mi][2][j];
      s[3] = f2 + c2v3 - 2.f * acc[mi][3][j];
      ce(s[0], s[1]); ce(s[2], s[3]); ce(s[0], s[2]); ce(s[1], s[3]); ce(s[1], s[2]);
      s[4] = BIGF; s[5] = BIGF;
      merge6<1>(s); merge6<2>(s); merge6<4>(s); merge6<8>(s);
      if (col == 0) {
        float* cp = cand + ((size_t)n * 64 + cg) * 6;
#pragma unroll
        for (int r = 0; r < 6; ++r) cp[r] = s[r];
      }
    }
  }
}

// ---------- merge 64 sorted 6-lists per row -> score + rowloss ----------
__global__ void finalize(const float* __restrict__ cand, const float* __restrict__ rvec,
                         float* __restrict__ rowloss, float* __restrict__ score) {
  const int n = blockIdx.x, l = threadIdx.x;
  const float* cp = cand + ((size_t)n * 64 + l) * 6;
  float s[6];
#pragma unroll
  for (int i = 0; i < 6; ++i) s[i] = cp[i];
  merge6<1>(s); merge6<2>(s); merge6<4>(s); merge6<8>(s); merge6<16>(s); merge6<32>(s);
  if (l == 0) {
    const float r2 = rvec[0] * rvec[0];
    float att = 0.f, rep = 0.f;
#pragma unroll
    for (int i = 0; i < 3; ++i) att += fmaxf(s[i] - r2, 0.f);
#pragma unroll
    for (int i = 3; i < 6; ++i) rep += fmaxf(r2 - s[i] - 0.1f, 0.f);
    rowloss[n] = att + rep;
    float dk0 = sqrtf(fmaxf(s[0], 0.f));
    float dk1 = sqrtf(fmaxf(s[1], 0.f));
    float dk2 = sqrtf(fmaxf(s[2], 0.f));
    float e1 = expf(dk0 - dk1), e2 = expf(dk0 - dk2);
    score[n] = dk0 / (1.f + e1 + e2);
  }
}

__global__ void reduce_loss(const float* __restrict__ rowloss, float* __restrict__ out) {
  const int t = threadIdx.x;
  float s = 0.f;
  for (int i = t; i < NROW; i += 256) s += rowloss[i];
  __shared__ float red[256];
  red[t] = s; __syncthreads();
  for (int off = 128; off > 0; off >>= 1) { if (t < off) red[t] += red[t + off]; __syncthreads(); }
  if (t == 0) out[0] = red[0] / (0.001f * 49152.f);  // (1/NU)/(B*HW*K)
}

extern "C" void kernel_launch(void* const* d_in, const int* in_sizes, int n_in,
                              void* d_out, int out_size, void* d_ws, size_t ws_size,
                              hipStream_t stream) {
  const float* sample = (const float*)d_in[0];
  const float* W      = (const float*)d_in[1];
  const float* bvec   = (const float*)d_in[2];
  const float* C      = (const float*)d_in[3];
  const float* rv     = (const float*)d_in[4];
  float* out = (float*)d_out;

  char* p = (char*)d_ws;
  auto take = [&](size_t bytes) { char* q = p; p += (bytes + 255) & ~(size_t)255; return q; };
  __hip_bfloat16* Xb   = (__hip_bfloat16*)take((size_t)NROW * DIMC * 2);
  __hip_bfloat16* Wb   = (__hip_bfloat16*)take((size_t)DIMC * DIMC * 2);
  __hip_bfloat16* Ct   = (__hip_bfloat16*)take((size_t)NCEN * DIMC * 2);
  __hip_bfloat16* phib = (__hip_bfloat16*)take((size_t)NROW * DIMC * 2);
  float* feat2   = (float*)take((size_t)NROW * 4);
  float* cent2   = (float*)take((size_t)NCEN * 4);
  float* cand    = (float*)take((size_t)NROW * 64 * 6 * 4);
  float* rowloss = (float*)take((size_t)NROW * 4);

  transpose_cvt<<<dim3(128, 56, 4), dim3(32, 8), 0, stream>>>(sample, Xb);
  transpose_cvt<<<dim3(128, 56, 1), dim3(32, 8), 0, stream>>>(C, Ct);
  w_convert<<<dim3(12544), dim3(256), 0, stream>>>(W, Wb);
  rowsq<<<dim3(NCEN), dim3(256), 0, stream>>>(Ct, cent2);
  gemm_phi<<<dim3(128, 14), dim3(256), 0, stream>>>(Xb, Wb, W, bvec, phib);
  rowsq<<<dim3(NROW), dim3(256), 0, stream>>>(phib, feat2);
  gemm_dist<<<dim3(128, 32), dim3(256), 0, stream>>>(phib, Ct, feat2, cent2, cand);
  finalize<<<dim3(NROW), dim3(64), 0, stream>>>(cand, rv, rowloss, out + 1);
  reduce_loss<<<dim3(1), dim3(256), 0, stream>>>(rowloss, out);
}

// Round 8
// 653.485 us; speedup vs baseline: 1.2329x; 1.0938x over previous
//
#include <hip/hip_runtime.h>
#include <hip/hip_bf16.h>

using v8s = __attribute__((ext_vector_type(8))) short;
using v4f = __attribute__((ext_vector_type(4))) float;

#define DIMC 1792
#define NROW 16384
#define NCEN 4096
#define BIGF 3.0e38f

// direct global->LDS, 16B per lane; LDS dest must be wave-uniform base (+lane*16 implicit)
#define GL2LDS16(g, l) __builtin_amdgcn_global_load_lds(                      \
    (const __attribute__((address_space(1))) void*)(g),                       \
    (__attribute__((address_space(3))) void*)(l), 16, 0, 0)

// counted-vmcnt fence + raw barrier (NO __syncthreads: compiler would drain vmcnt(0))
#define FENCE_BAR(N) do {                                                     \
    asm volatile("s_waitcnt vmcnt(" #N ")" ::: "memory");                     \
    __builtin_amdgcn_sched_barrier(0);                                        \
    __builtin_amdgcn_s_barrier();                                             \
    __builtin_amdgcn_sched_barrier(0);                                        \
  } while (0)

__device__ __forceinline__ void ce(float& a, float& b) {
  float lo = fminf(a, b), hi = fmaxf(a, b); a = lo; b = hi;
}

// merge this lane's sorted-ascending 6-list with partner lane's (xor MASK);
// result: sorted-ascending 6 smallest of the 12 (identical on both lanes).
template<int MASK>
__device__ __forceinline__ void merge6(float s[6]) {
  float p[6];
#pragma unroll
  for (int i = 0; i < 6; ++i) p[i] = __shfl_xor(s[i], MASK);
  float t[6];
#pragma unroll
  for (int i = 0; i < 6; ++i) t[i] = fminf(s[i], p[5 - i]);
  ce(t[0], t[3]); ce(t[1], t[4]); ce(t[2], t[5]);
  ce(t[0], t[2]); ce(t[0], t[1]); ce(t[1], t[2]);
  ce(t[3], t[5]); ce(t[3], t[4]); ce(t[4], t[5]);
#pragma unroll
  for (int i = 0; i < 6; ++i) s[i] = t[i];
}

// ---------- transpose [1792][4096] f32 -> [4096][1792] bf16 (per z) ----------
__global__ void transpose_cvt(const float* __restrict__ in, __hip_bfloat16* __restrict__ out) {
  __shared__ float tile[32][33];
  const int tx = threadIdx.x, ty = threadIdx.y;
  const size_t zoff = (size_t)blockIdx.z * DIMC * NCEN;
  const float* inb = in + zoff;
  __hip_bfloat16* outb = out + zoff;
  const int r0 = blockIdx.y * 32, c0 = blockIdx.x * 32;
#pragma unroll
  for (int j = 0; j < 4; ++j) {
    int rr = ty + j * 8;
    tile[rr][tx] = inb[(size_t)(r0 + rr) * 4096 + c0 + tx];
  }
  __syncthreads();
#pragma unroll
  for (int j = 0; j < 4; ++j) {
    int rr = ty + j * 8;
    outb[(size_t)(c0 + rr) * DIMC + r0 + tx] = __float2bfloat16(tile[tx][rr]);
  }
}

// ---------- W [1792][1794] f32 -> Wb [1792][1792] bf16 ----------
__global__ void w_convert(const float* __restrict__ W, __hip_bfloat16* __restrict__ Wb) {
  int idx = blockIdx.x * 256 + threadIdx.x;
  int o = idx / DIMC, i = idx - o * DIMC;
  Wb[idx] = __float2bfloat16(W[(size_t)o * 1794 + i]);
}

// ---------- dst[row] = sum over 1792 bf16 of v*v ----------
__global__ void rowsq(const __hip_bfloat16* __restrict__ src, float* __restrict__ dst) {
  const int row = blockIdx.x, t = threadIdx.x;
  float s = 0.f;
  if (t < 224) {
    const uint4 v = *(const uint4*)((const unsigned short*)src + (size_t)row * DIMC + t * 8);
    unsigned int u0 = v.x, u1 = v.y, u2 = v.z, u3 = v.w;
    float a, b;
    a = __uint_as_float(u0 << 16); b = __uint_as_float(u0 & 0xFFFF0000u); s += a * a + b * b;
    a = __uint_as_float(u1 << 16); b = __uint_as_float(u1 & 0xFFFF0000u); s += a * a + b * b;
    a = __uint_as_float(u2 << 16); b = __uint_as_float(u2 & 0xFFFF0000u); s += a * a + b * b;
    a = __uint_as_float(u3 << 16); b = __uint_as_float(u3 & 0xFFFF0000u); s += a * a + b * b;
  }
  __shared__ float red[256];
  red[t] = s; __syncthreads();
  for (int off = 128; off > 0; off >>= 1) { if (t < off) red[t] += red[t + off]; __syncthreads(); }
  if (t == 0) dst[row] = red[0];
}

// ======== shared 256x256 GEMM machinery: 512 thr (8 waves 2Mx4N), BK=32, ========
// ======== triple-buffered LDS (96KB dyn), counted vmcnt(4), 1 barrier/tile ======
// LDS buffer layout: buf k (k=0,1,2) at L + k*32768; A at +0 (16KB), B at +16384.
// Staging: thread t -> LDS byte t*16 (linear, rule #21); row = t>>2 (0..127),
// granule gS = (t&3)^((rowS>>1)&3) pre-swizzled on the GLOBAL side.
// Frag reads: offA/B = (row*32 + pr*8)*2 bytes, pr = g^((col>>1)&3)  (2-way banks).

#define GEMM_PRE(APTR, BPTR)                                                  \
  extern __shared__ __align__(16) char L[];                                   \
  const int t = threadIdx.x;                                                  \
  const int l = t & 63, w = t >> 6, wm = w >> 2, wn = w & 3;                  \
  const int n0 = blockIdx.x * 256, o0 = blockIdx.y * 256;                     \
  const int rowS = t >> 2, gS = (t & 3) ^ ((rowS >> 1) & 3);                  \
  const unsigned short* aP0 = (const unsigned short*)(APTR) + (size_t)(n0 + rowS) * DIMC + gS * 8; \
  const unsigned short* aP1 = aP0 + (size_t)128 * DIMC;                       \
  const unsigned short* bP0 = (const unsigned short*)(BPTR) + (size_t)(o0 + rowS) * DIMC + gS * 8; \
  const unsigned short* bP1 = bP0 + (size_t)128 * DIMC;                       \
  char* A0 = L;          char* B0 = L + 16384;                                \
  char* A1 = L + 32768;  char* B1 = L + 49152;                                \
  char* A2 = L + 65536;  char* B2 = L + 81920;                                \
  const int woff = w * 1024;                                                  \
  const int col = l & 15, g = l >> 4, pr = g ^ ((col >> 1) & 3);              \
  int offA[8], offB[4];                                                       \
  _Pragma("unroll")                                                           \
  for (int i = 0; i < 8; ++i) offA[i] = ((wm * 128 + i * 16 + col) * 32 + pr * 8) * 2; \
  _Pragma("unroll")                                                           \
  for (int i = 0; i < 4; ++i) offB[i] = ((wn * 64 + i * 16 + col) * 32 + pr * 8) * 2;  \
  v4f acc[8][4] = {};                                                         \
  auto stage = [&](int ke, char* sA, char* sB) {                              \
    GL2LDS16(aP0 + ke, sA + woff);                                            \
    GL2LDS16(aP1 + ke, sA + 8192 + woff);                                     \
    GL2LDS16(bP0 + ke, sB + woff);                                            \
    GL2LDS16(bP1 + ke, sB + 8192 + woff);                                     \
  };                                                                          \
  auto compute = [&](const char* rA, const char* rB) {                        \
    v8s af[4], bf[4];                                                         \
    _Pragma("unroll")                                                         \
    for (int i = 0; i < 4; ++i) af[i] = *(const v8s*)(rA + offA[i]);          \
    _Pragma("unroll")                                                         \
    for (int i = 0; i < 4; ++i) bf[i] = *(const v8s*)(rB + offB[i]);          \
    __builtin_amdgcn_s_setprio(1);                                            \
    _Pragma("unroll")                                                         \
    for (int mi = 0; mi < 4; ++mi)                                            \
      _Pragma("unroll")                                                       \
      for (int ni = 0; ni < 4; ++ni)                                          \
        acc[mi][ni] = __builtin_amdgcn_mfma_f32_16x16x32_bf16(af[mi], bf[ni], acc[mi][ni], 0, 0, 0); \
    __builtin_amdgcn_s_setprio(0);                                            \
    __builtin_amdgcn_sched_barrier(0);                                        \
    v8s a2[4];                                                                \
    _Pragma("unroll")                                                         \
    for (int i = 0; i < 4; ++i) a2[i] = *(const v8s*)(rA + offA[4 + i]);      \
    __builtin_amdgcn_s_setprio(1);                                            \
    _Pragma("unroll")                                                         \
    for (int mi = 0; mi < 4; ++mi)                                            \
      _Pragma("unroll")                                                       \
      for (int ni = 0; ni < 4; ++ni)                                          \
        acc[4 + mi][ni] = __builtin_amdgcn_mfma_f32_16x16x32_bf16(a2[mi], bf[ni], acc[4 + mi][ni], 0, 0, 0); \
    __builtin_amdgcn_s_setprio(0);                                            \
  };                                                                          \
  stage(0, A0, B0);                                                           \
  stage(32, A1, B1);                                                          \
  FENCE_BAR(4);                                                               \
  for (int k3 = 0; k3 < 54; k3 += 3) { /* 56 K-tiles; 54/55 in tail */        \
    stage((k3 + 2) * 32, A2, B2); compute(A0, B0); FENCE_BAR(4);              \
    stage((k3 + 3) * 32, A0, B0); compute(A1, B1); FENCE_BAR(4);              \
    stage((k3 + 4) * 32, A1, B1); compute(A2, B2); FENCE_BAR(4);              \
  }                                                                           \
  compute(A0, B0); /* tile 54 */                                              \
  FENCE_BAR(0);    /* force tile 55 landed */                                 \
  compute(A1, B1); /* tile 55 */

// ---------- GEMM1: phi = Xb * Wb^T + bias + coord terms -> phib bf16 ----------
__global__ __launch_bounds__(512, 2) void gemm_phi(
    const __hip_bfloat16* __restrict__ Xb, const __hip_bfloat16* __restrict__ Wb,
    const float* __restrict__ W, const float* __restrict__ bvec,
    __hip_bfloat16* __restrict__ phib) {
  GEMM_PRE(Xb, Wb)
#pragma unroll
  for (int ni = 0; ni < 4; ++ni) {
    const int o = o0 + wn * 64 + ni * 16 + col;
    const float bo = bvec[o];
    const float wx = W[(size_t)o * 1794 + 1792];
    const float wy = W[(size_t)o * 1794 + 1793];
#pragma unroll
    for (int mi = 0; mi < 8; ++mi) {
#pragma unroll
      for (int j = 0; j < 4; ++j) {
        const int n = n0 + wm * 128 + mi * 16 + g * 4 + j;
        const int wi = n & 63, hi = (n >> 6) & 63;
        const float xxv = -1.f + (2.f / 63.f) * wi;
        const float yyv = -1.f + (2.f / 63.f) * hi;
        float v = acc[mi][ni][j] + bo + wx * xxv + wy * yyv;
        phib[(size_t)n * DIMC + o] = __float2bfloat16(v);
      }
    }
  }
}

// ---------- GEMM2: dist2 = feat2 + cent2 - 2*phi.C ; fused bitonic top-6 ----------
__global__ __launch_bounds__(512, 2) void gemm_dist(
    const __hip_bfloat16* __restrict__ phib, const __hip_bfloat16* __restrict__ Ct,
    const float* __restrict__ feat2, const float* __restrict__ cent2,
    float* __restrict__ cand) {
  GEMM_PRE(phib, Ct)
  // epilogue: per row (16-lane group g), the wave's 64 cols -> sorted 6 smallest
  float c2v[4];
#pragma unroll
  for (int ni = 0; ni < 4; ++ni) c2v[ni] = cent2[o0 + wn * 64 + ni * 16 + col];
  const int cg = blockIdx.y * 4 + wn;  // 64-col group index (NCEN/64 = 64 groups)
#pragma unroll
  for (int mi = 0; mi < 8; ++mi) {
#pragma unroll
    for (int j = 0; j < 4; ++j) {
      const int n = n0 + wm * 128 + mi * 16 + g * 4 + j;
      const float f2 = feat2[n];
      float s[6];
      s[0] = f2 + c2v[0] - 2.f * acc[mi][0][j];
      s[1] = f2 + c2v[1] - 2.f * acc[mi][1][j];
      s[2] = f2 + c2v[2] - 2.f * acc[mi][2][j];
      s[3] = f2 + c2v[3] - 2.f * acc[mi][3][j];
      ce(s[0], s[1]); ce(s[2], s[3]); ce(s[0], s[2]); ce(s[1], s[3]); ce(s[1], s[2]);
      s[4] = BIGF; s[5] = BIGF;
      merge6<1>(s); merge6<2>(s); merge6<4>(s); merge6<8>(s);
      if (col == 0) {
        float* cp = cand + ((size_t)n * 64 + cg) * 6;
#pragma unroll
        for (int r = 0; r < 6; ++r) cp[r] = s[r];
      }
    }
  }
}

// ---------- merge 64 sorted 6-lists per row -> score + rowloss ----------
__global__ void finalize(const float* __restrict__ cand, const float* __restrict__ rvec,
                         float* __restrict__ rowloss, float* __restrict__ score) {
  const int n = blockIdx.x, l = threadIdx.x;
  const float* cp = cand + ((size_t)n * 64 + l) * 6;
  float s[6];
#pragma unroll
  for (int i = 0; i < 6; ++i) s[i] = cp[i];
  merge6<1>(s); merge6<2>(s); merge6<4>(s); merge6<8>(s); merge6<16>(s); merge6<32>(s);
  if (l == 0) {
    const float r2 = rvec[0] * rvec[0];
    float att = 0.f, rep = 0.f;
#pragma unroll
    for (int i = 0; i < 3; ++i) att += fmaxf(s[i] - r2, 0.f);
#pragma unroll
    for (int i = 3; i < 6; ++i) rep += fmaxf(r2 - s[i] - 0.1f, 0.f);
    rowloss[n] = att + rep;
    float dk0 = sqrtf(fmaxf(s[0], 0.f));
    float dk1 = sqrtf(fmaxf(s[1], 0.f));
    float dk2 = sqrtf(fmaxf(s[2], 0.f));
    float e1 = expf(dk0 - dk1), e2 = expf(dk0 - dk2);
    score[n] = dk0 / (1.f + e1 + e2);
  }
}

__global__ void reduce_loss(const float* __restrict__ rowloss, float* __restrict__ out) {
  const int t = threadIdx.x;
  float s = 0.f;
  for (int i = t; i < NROW; i += 256) s += rowloss[i];
  __shared__ float red[256];
  red[t] = s; __syncthreads();
  for (int off = 128; off > 0; off >>= 1) { if (t < off) red[t] += red[t + off]; __syncthreads(); }
  if (t == 0) out[0] = red[0] / (0.001f * 49152.f);  // (1/NU)/(B*HW*K)
}

extern "C" void kernel_launch(void* const* d_in, const int* in_sizes, int n_in,
                              void* d_out, int out_size, void* d_ws, size_t ws_size,
                              hipStream_t stream) {
  const float* sample = (const float*)d_in[0];
  const float* W      = (const float*)d_in[1];
  const float* bvec   = (const float*)d_in[2];
  const float* C      = (const float*)d_in[3];
  const float* rv     = (const float*)d_in[4];
  float* out = (float*)d_out;

  char* p = (char*)d_ws;
  auto take = [&](size_t bytes) { char* q = p; p += (bytes + 255) & ~(size_t)255; return q; };
  __hip_bfloat16* Xb   = (__hip_bfloat16*)take((size_t)NROW * DIMC * 2);
  __hip_bfloat16* Wb   = (__hip_bfloat16*)take((size_t)DIMC * DIMC * 2);
  __hip_bfloat16* Ct   = (__hip_bfloat16*)take((size_t)NCEN * DIMC * 2);
  __hip_bfloat16* phib = (__hip_bfloat16*)take((size_t)NROW * DIMC * 2);
  float* feat2   = (float*)take((size_t)NROW * 4);
  float* cent2   = (float*)take((size_t)NCEN * 4);
  float* cand    = (float*)take((size_t)NROW * 64 * 6 * 4);
  float* rowloss = (float*)take((size_t)NROW * 4);

  // allow 96KB dynamic LDS (idempotent; host-side attribute, graph-capture safe)
  hipFuncSetAttribute((const void*)gemm_phi,  hipFuncAttributeMaxDynamicSharedMemorySize, 98304);
  hipFuncSetAttribute((const void*)gemm_dist, hipFuncAttributeMaxDynamicSharedMemorySize, 98304);

  transpose_cvt<<<dim3(128, 56, 4), dim3(32, 8), 0, stream>>>(sample, Xb);
  transpose_cvt<<<dim3(128, 56, 1), dim3(32, 8), 0, stream>>>(C, Ct);
  w_convert<<<dim3(12544), dim3(256), 0, stream>>>(W, Wb);
  rowsq<<<dim3(NCEN), dim3(256), 0, stream>>>(Ct, cent2);
  gemm_phi<<<dim3(64, 7), dim3(512), 98304, stream>>>(Xb, Wb, W, bvec, phib);
  rowsq<<<dim3(NROW), dim3(256), 0, stream>>>(phib, feat2);
  gemm_dist<<<dim3(64, 16), dim3(512), 98304, stream>>>(phib, Ct, feat2, cent2, cand);
  finalize<<<dim3(NROW), dim3(64), 0, stream>>>(cand, rv, rowloss, out + 1);
  reduce_loss<<<dim3(1), dim3(256), 0, stream>>>(rowloss, out);
}